// Round 9
// baseline (32.451 us; speedup 1.0000x reference)
//
#include <hip/hip_runtime.h>
#include <hip/hip_bf16.h>

// CSPN step: out[b,y,x] = sum_{i,j} gw[b, i*3+j, y+1, x+1] * src[y+1-i, x+1-j]
// src = h0 for center tap (i=j=1), hn otherwise; zero outside [0,H)x[0,W).
// R8 = R7 (4 px/thread, dwordx4/tap, load-first, batch-b->XCD-b swizzle)
// + nontemporal on the zero-reuse streams (gw loads, out store) so the
// 4MB per-XCD L2 is reserved for hn/h0 (3.4MB working set).

constexpr int B = 8;
constexpr int H = 352;
constexpr int W = 1216;
constexpr int HP = H + 2;            // 354
constexpr int WP = W + 2;            // 1218
constexpr int CPR = W / 4;           // 304 chunks per row, exact
constexpr size_t PLANE = (size_t)HP * WP;
constexpr int NBLK = B * H * CPR / 256;   // 3344 = 8 * 418; 418 blocks = 1 batch

typedef float f4  __attribute__((ext_vector_type(4)));               // 16B aligned
typedef float f4u __attribute__((ext_vector_type(4), aligned(4)));   // dword aligned

__global__ __launch_bounds__(256) void cspn_r8_kernel(
    const float* __restrict__ gw,   // [B, 9, HP, WP]
    const float* __restrict__ hn,   // [B, 1, H, W]
    const float* __restrict__ h0,   // [B, 1, H, W]
    float* __restrict__ out)        // [B, 1, H, W]
{
    // XCD swizzle: hw maps dispatch id d -> XCD d%8; remap so XCD k runs
    // logical blocks [418k, 418k+418) == exactly batch k (linear within).
    int bid = blockIdx.x;
    int swz = (bid & 7) * (NBLK / 8) + (bid >> 3);
    int tid = swz * 256 + threadIdx.x;

    int cx = tid % CPR;
    int t2 = tid / CPR;
    int y  = t2 % H;
    int b  = t2 / H;
    int x0 = cx * 4;

    const float* hnb = hn + (size_t)b * H * W;
    const float* h0p = h0 + (size_t)b * H * W + (size_t)y * W + x0;
    const float* gwp = gw + (size_t)b * 9 * PLANE + (size_t)(y + 1) * WP + (x0 + 1);
    float* outp = out + (size_t)b * H * W + (size_t)y * W + x0;

    // ---- issue ALL loads first (14 independent memory ops) ----
    f4u g[9];
#pragma unroll
    for (int t = 0; t < 9; ++t)
        g[t] = __builtin_nontemporal_load(
                   reinterpret_cast<const f4u*>(gwp + (size_t)t * PLANE));

    int aL = (cx > 0)       ? x0 - 1 : 0;
    int aR = (cx < CPR - 1) ? x0 + 4 : W - 1;
    int ay0 = (y < H - 1) ? y + 1 : y;     // clamped row for i=0
    int ay2 = (y > 0)     ? y - 1 : y;     // clamped row for i=2
    const float* rp0 = hnb + (size_t)ay0 * W;
    const float* rp1 = hnb + (size_t)y * W;
    const float* rp2 = hnb + (size_t)ay2 * W;

    f4 v0 = *reinterpret_cast<const f4*>(rp0 + x0);
    float sL0 = rp0[aL], sR0 = rp0[aR];
    f4 v1 = *reinterpret_cast<const f4*>(rp1 + x0);
    float sL1 = rp1[aL], sR1 = rp1[aR];
    f4 v2 = *reinterpret_cast<const f4*>(rp2 + x0);
    float sL2 = rp2[aL], sR2 = rp2[aR];

    f4 c = *reinterpret_cast<const f4*>(h0p);

    // ---- masks / register shuffle (no memory) ----
    bool okL = (cx > 0), okR = (cx < CPR - 1);
    bool ok0 = (y < H - 1), ok2 = (y > 0);
    float m0 = ok0 ? 1.f : 0.f;
    float m2 = ok2 ? 1.f : 0.f;

    float r[3][6];
    r[0][0] = (ok0 & okL) ? sL0 : 0.f;
    r[0][1] = v0[0] * m0; r[0][2] = v0[1] * m0;
    r[0][3] = v0[2] * m0; r[0][4] = v0[3] * m0;
    r[0][5] = (ok0 & okR) ? sR0 : 0.f;

    r[1][0] = okL ? sL1 : 0.f;
    r[1][1] = v1[0]; r[1][2] = v1[1];
    r[1][3] = v1[2]; r[1][4] = v1[3];
    r[1][5] = okR ? sR1 : 0.f;

    r[2][0] = (ok2 & okL) ? sL2 : 0.f;
    r[2][1] = v2[0] * m2; r[2][2] = v2[1] * m2;
    r[2][3] = v2[2] * m2; r[2][4] = v2[3] * m2;
    r[2][5] = (ok2 & okR) ? sR2 : 0.f;

    // ---- FMAs ----
    float acc[4] = {0.f, 0.f, 0.f, 0.f};
#pragma unroll
    for (int i = 0; i < 3; ++i) {
#pragma unroll
        for (int j = 0; j < 3; ++j) {
            const int t = i * 3 + j;
#pragma unroll
            for (int p = 0; p < 4; ++p) {
                float s = (t == 4) ? c[p] : r[i][p + 2 - j];
                acc[p] = fmaf(g[t][p], s, acc[p]);
            }
        }
    }

    f4 o; o[0] = acc[0]; o[1] = acc[1]; o[2] = acc[2]; o[3] = acc[3];
    __builtin_nontemporal_store(o, reinterpret_cast<f4*>(outp));
}

extern "C" void kernel_launch(void* const* d_in, const int* in_sizes, int n_in,
                              void* d_out, int out_size, void* d_ws, size_t ws_size,
                              hipStream_t stream) {
    const float* gw = (const float*)d_in[0];
    const float* hn = (const float*)d_in[1];
    const float* h0 = (const float*)d_in[2];
    float* out = (float*)d_out;

    cspn_r8_kernel<<<NBLK, 256, 0, stream>>>(gw, hn, h0, out);
}

// Round 10
// 28.128 us; speedup vs baseline: 1.1537x; 1.1537x over previous
//
#include <hip/hip_runtime.h>
#include <hip/hip_bf16.h>

// CSPN step: out[b,y,x] = sum_{i,j} gw[b, i*3+j, y+1, x+1] * src[y+1-i, x+1-j]
// src = h0 for center tap (i=j=1), hn otherwise; zero outside [0,H)x[0,W).
// FINAL (R7 structure, best measured: 28.05 us ≈ 94% of 6.29 TB/s copy ceiling):
//  - linear 1D mapping, 4 px/thread, one dwordx4 per gw tap (1KB/wave/tap)
//  - all 14 loads issued before any FMA (wave-level MLP)
//  - bijective XCD swizzle pinning batch b to XCD b: hn_b+h0_b (3.4MB) stays
//    resident in that XCD's 4MB L2; each XCD sweeps one linear gw stream
//  - plain (temporal) loads/stores: NT hints measured -16% here (R8)

constexpr int B = 8;
constexpr int H = 352;
constexpr int W = 1216;
constexpr int HP = H + 2;            // 354
constexpr int WP = W + 2;            // 1218
constexpr int CPR = W / 4;           // 304 chunks per row, exact
constexpr size_t PLANE = (size_t)HP * WP;
constexpr int NBLK = B * H * CPR / 256;   // 3344 = 8 * 418; 418 blocks = 1 batch

typedef float f4  __attribute__((ext_vector_type(4)));               // 16B aligned
typedef float f4u __attribute__((ext_vector_type(4), aligned(4)));   // dword aligned

__global__ __launch_bounds__(256) void cspn_final_kernel(
    const float* __restrict__ gw,   // [B, 9, HP, WP]
    const float* __restrict__ hn,   // [B, 1, H, W]
    const float* __restrict__ h0,   // [B, 1, H, W]
    float* __restrict__ out)        // [B, 1, H, W]
{
    // XCD swizzle: hw maps dispatch id d -> XCD d%8; remap so XCD k runs
    // logical blocks [418k, 418k+418) == exactly batch k (linear within).
    int bid = blockIdx.x;
    int swz = (bid & 7) * (NBLK / 8) + (bid >> 3);
    int tid = swz * 256 + threadIdx.x;

    int cx = tid % CPR;
    int t2 = tid / CPR;
    int y  = t2 % H;
    int b  = t2 / H;
    int x0 = cx * 4;

    const float* hnb = hn + (size_t)b * H * W;
    const float* h0p = h0 + (size_t)b * H * W + (size_t)y * W + x0;
    const float* gwp = gw + (size_t)b * 9 * PLANE + (size_t)(y + 1) * WP + (x0 + 1);
    float* outp = out + (size_t)b * H * W + (size_t)y * W + x0;

    // ---- issue ALL loads first (14 independent memory ops) ----
    f4u g[9];
#pragma unroll
    for (int t = 0; t < 9; ++t)
        g[t] = *reinterpret_cast<const f4u*>(gwp + (size_t)t * PLANE);

    int aL = (cx > 0)       ? x0 - 1 : 0;
    int aR = (cx < CPR - 1) ? x0 + 4 : W - 1;
    int ay0 = (y < H - 1) ? y + 1 : y;     // clamped row for i=0
    int ay2 = (y > 0)     ? y - 1 : y;     // clamped row for i=2
    const float* rp0 = hnb + (size_t)ay0 * W;
    const float* rp1 = hnb + (size_t)y * W;
    const float* rp2 = hnb + (size_t)ay2 * W;

    f4 v0 = *reinterpret_cast<const f4*>(rp0 + x0);
    float sL0 = rp0[aL], sR0 = rp0[aR];
    f4 v1 = *reinterpret_cast<const f4*>(rp1 + x0);
    float sL1 = rp1[aL], sR1 = rp1[aR];
    f4 v2 = *reinterpret_cast<const f4*>(rp2 + x0);
    float sL2 = rp2[aL], sR2 = rp2[aR];

    f4 c = *reinterpret_cast<const f4*>(h0p);

    // ---- masks / register shuffle (no memory) ----
    bool okL = (cx > 0), okR = (cx < CPR - 1);
    bool ok0 = (y < H - 1), ok2 = (y > 0);
    float m0 = ok0 ? 1.f : 0.f;
    float m2 = ok2 ? 1.f : 0.f;

    float r[3][6];
    r[0][0] = (ok0 & okL) ? sL0 : 0.f;
    r[0][1] = v0[0] * m0; r[0][2] = v0[1] * m0;
    r[0][3] = v0[2] * m0; r[0][4] = v0[3] * m0;
    r[0][5] = (ok0 & okR) ? sR0 : 0.f;

    r[1][0] = okL ? sL1 : 0.f;
    r[1][1] = v1[0]; r[1][2] = v1[1];
    r[1][3] = v1[2]; r[1][4] = v1[3];
    r[1][5] = okR ? sR1 : 0.f;

    r[2][0] = (ok2 & okL) ? sL2 : 0.f;
    r[2][1] = v2[0] * m2; r[2][2] = v2[1] * m2;
    r[2][3] = v2[2] * m2; r[2][4] = v2[3] * m2;
    r[2][5] = (ok2 & okR) ? sR2 : 0.f;

    // ---- FMAs ----
    float acc[4] = {0.f, 0.f, 0.f, 0.f};
#pragma unroll
    for (int i = 0; i < 3; ++i) {
#pragma unroll
        for (int j = 0; j < 3; ++j) {
            const int t = i * 3 + j;
#pragma unroll
            for (int p = 0; p < 4; ++p) {
                float s = (t == 4) ? c[p] : r[i][p + 2 - j];
                acc[p] = fmaf(g[t][p], s, acc[p]);
            }
        }
    }

    f4 o; o[0] = acc[0]; o[1] = acc[1]; o[2] = acc[2]; o[3] = acc[3];
    *reinterpret_cast<f4*>(outp) = o;   // 16B aligned
}

extern "C" void kernel_launch(void* const* d_in, const int* in_sizes, int n_in,
                              void* d_out, int out_size, void* d_ws, size_t ws_size,
                              hipStream_t stream) {
    const float* gw = (const float*)d_in[0];
    const float* hn = (const float*)d_in[1];
    const float* h0 = (const float*)d_in[2];
    float* out = (float*)d_out;

    cspn_final_kernel<<<NBLK, 256, 0, stream>>>(gw, hn, h0, out);
}